// Round 3
// baseline (724.023 us; speedup 1.0000x reference)
//
#include <hip/hip_runtime.h>
#include <hip/hip_cooperative_groups.h>
#include <math.h>

namespace cg = cooperative_groups;

// Bit-exact np-ref emulation (pinned R14, PASSING since):
//  - einsum: SOP fl(fl(w0x0)+fl(w1x1))  (no FMA)
//  - reduce: numpy BUFFERED reduce: per channel, 25 chunks of 8192; chunk =
//    64 leaves of 128-elem 8-acc blocks, balanced tree; chunks sequential.
//    var two-pass. rstd = fdiv(1,fsqrt(var+eps)). LIF fp32, each op rounded.
// R20 (this round): single cooperative kernel, 5 phases separated by
//  grid.sync() + device fences. Per-element arithmetic and rounding order
//  IDENTICAL to the 5-kernel version; only scheduling/launch structure
//  changed. Purpose: (a) kill inter-dispatch overhead if that is the 185us
//  gap; (b) otherwise surface ONE >131us dispatch with full counters.
constexpr int T = 16, B = 512, C = 2, V = 25, E = 256;
constexpr int EV  = E * V;           // 6400
constexpr int BEV = B * EV;          // 3,276,800
constexpr int XT  = B * C * V;       // 25600 floats between t-slices of x
constexpr int NB  = 1600;            // 128-element blocks per channel
constexpr int CHUNKS = 25;           // 204800 / 8192
constexpr int BPC = 64;              // 128-blocks per chunk
constexpr int NROWS = 7;             // max (t,b)-rows touched by a 128-block
constexpr float NF = 204800.0f;
constexpr int GRID = 512, TPB = 256;

typedef float f32x4 __attribute__((ext_vector_type(4)));

#define WS_M32(ws) ((float*)(ws))
#define WS_R32(ws) ((float*)(ws) + E)

// ---- phase 1/3: per-(pb,e) 128-element block-sum; bs layout [pb][e] ----
template<int PASS>
__device__ __forceinline__ void phase_bs(const float* __restrict__ x,
                                         const float* __restrict__ W,
                                         const float* __restrict__ ws,
                                         float* __restrict__ bs,
                                         float* __restrict__ sm) {
    #pragma unroll 1
    for (int rd = 0; rd < (NB + GRID - 1) / GRID; rd++) {   // 4 rounds
        int pb = rd * GRID + blockIdx.x;
        bool act = (pb < NB);
        int q0 = pb * 128;
        int row_lo = q0 / 25;
        if (act) {
            for (int i = threadIdx.x; i < NROWS * 50; i += TPB) {
                int r = i / 50;
                if (row_lo + r < 8192) sm[i] = x[(row_lo + r) * 50 + (i - r * 50)];
            }
        }
        __syncthreads();
        if (act) {
            int e = threadIdx.x;             // one thread per channel
            float w0 = W[e * 2 + 0];
            float w1 = W[e * 2 + 1];
            float mn = (PASS == 1) ? WS_M32(ws)[e] : 0.0f;
            int v   = q0 - row_lo * 25;
            int off = v;
            float rg[8];
            #pragma unroll
            for (int k = 0; k < 128; k++) {
                float y = __fadd_rn(__fmul_rn(w0, sm[off]), __fmul_rn(w1, sm[off + 25]));
                if (PASS == 1) {
                    float d = __fsub_rn(y, mn);
                    y = __fmul_rn(d, d);
                }
                int j = k & 7;
                rg[j] = (k < 8) ? y : __fadd_rn(rg[j], y);   // numpy 8-acc pattern
                v++; off++;
                if (v == 25) { v = 0; off += 25; }
            }
            bs[pb * 256 + e] =
                __fadd_rn(__fadd_rn(__fadd_rn(rg[0], rg[1]), __fadd_rn(rg[2], rg[3])),
                          __fadd_rn(__fadd_rn(rg[4], rg[5]), __fadd_rn(rg[6], rg[7])));
        }
        __syncthreads();
    }
}

// ---- phase 2/4: per-channel combine; register tree (no scratch) ----
template<int WHICH>
__device__ __forceinline__ void phase_comb(const float* __restrict__ bs,
                                           float* __restrict__ ws,
                                           float* __restrict__ sm) {
    int e = blockIdx.x;
    if (e < E) {                             // blocks 256..511 idle here
        float* cb   = sm;
        float* csum = sm + NB;
        for (int i = threadIdx.x; i < NB; i += TPB) cb[i] = bs[i * 256 + e];
        __syncthreads();
        if (threadIdx.x < CHUNKS) {
            int c = threadIdx.x;
            float t[BPC];                       // fully-unrolled -> VGPRs
            #pragma unroll
            for (int i = 0; i < BPC; i++) t[i] = cb[c * BPC + i];
            #pragma unroll
            for (int m = BPC / 2; m >= 1; m >>= 1) {    // balanced tree == numpy
                #pragma unroll
                for (int i = 0; i < m; i++)
                    t[i] = __fadd_rn(t[2 * i], t[2 * i + 1]);
            }
            csum[c] = t[0];
        }
        __syncthreads();
        if (threadIdx.x == 0) {
            float acc = 0.0f;                   // identity init
            #pragma unroll
            for (int c = 0; c < CHUNKS; c++) acc = __fadd_rn(acc, csum[c]);
            if (WHICH == 0) {
                WS_M32(ws)[e] = __fdiv_rn(acc, NF);
            } else {
                float var = __fdiv_rn(acc, NF);
                WS_R32(ws)[e] = __fdiv_rn(1.0f, __fsqrt_rn(__fadd_rn(var, 1e-5f)));
            }
        }
        __syncthreads();
    }
}

// ---- phase 5: LIF + BN apply; 4 elems/thread, vec4 nontemporal stores ----
__device__ __forceinline__ void phase_main(const float* __restrict__ x,
                                           const float* __restrict__ W,
                                           const float* __restrict__ g,
                                           const float* __restrict__ bta,
                                           const float* __restrict__ ws,
                                           float* __restrict__ out,
                                           float* __restrict__ sm) {
    #pragma unroll 1
    for (int rd = 0; rd < (3200 + GRID - 1) / GRID; rd++) {  // 7 rounds
        int blk = rd * GRID + blockIdx.x;
        bool act = (blk < 3200);
        int gi0 = blk * 1024;
        int b0  = gi0 / EV;
        int nb  = ((gi0 + 1023) / EV == b0) ? 1 : 2;   // straddles <=2 b's
        if (act) {
            for (int i = threadIdx.x; i < nb * 800; i += TPB) {
                int bi  = i / 800;
                int r   = i - bi * 800;
                int tt  = r / 50;
                sm[i] = x[(b0 + bi) * 50 + tt * XT + (r - tt * 50)];
            }
        }
        __syncthreads();
        if (act) {
            int gi  = gi0 + threadIdx.x * 4;  // 4 consecutive (b,e,v) indices
            int b   = gi / EV;
            int rem = gi - b * EV;
            int e0  = rem / V;
            int v0  = rem - e0 * V;
            int sb  = (b - b0) * 800;
            int e1  = (e0 < E - 1) ? e0 + 1 : e0;   // channel after a v-wrap
            float w00 = W[e0 * 2], w01 = W[e0 * 2 + 1];
            float w10 = W[e1 * 2], w11 = W[e1 * 2 + 1];
            float mn0 = WS_M32(ws)[e0], mn1 = WS_M32(ws)[e1];
            float rs0 = WS_R32(ws)[e0], rs1 = WS_R32(ws)[e1];
            float ga0 = g[e0],  ga1 = g[e1];        // == 1.0f: exact no-op
            float be0 = bta[e0], be1 = bta[e1];     // == 0.0f: exact no-op

            float wA[4], wB[4], mn[4], rs[4], ga[4], be[4];
            int   vv[4];
            #pragma unroll
            for (int j = 0; j < 4; j++) {           // static idx -> registers
                int  vj = v0 + j;
                bool cr = (vj >= V);                // crossed into channel e0+1
                vv[j] = cr ? vj - V : vj;
                wA[j] = cr ? w10 : w00;  wB[j] = cr ? w11 : w01;
                mn[j] = cr ? mn1 : mn0;  rs[j] = cr ? rs1 : rs0;
                ga[j] = cr ? ga1 : ga0;  be[j] = cr ? be1 : be0;
            }

            float vm[4] = {0.0f, 0.0f, 0.0f, 0.0f};
            #pragma unroll
            for (int t = 0; t < T; t++) {
                f32x4 o;
                #pragma unroll
                for (int j = 0; j < 4; j++) {
                    float x0 = sm[sb + t * 50 + vv[j]];
                    float x1 = sm[sb + t * 50 + 25 + vv[j]];
                    float y = __fadd_rn(__fmul_rn(wA[j], x0), __fmul_rn(wB[j], x1));
                    y = __fmul_rn(__fsub_rn(y, mn[j]), rs[j]);      // (y-mean)*rstd
                    y = __fadd_rn(__fmul_rn(y, ga[j]), be[j]);      // *gamma+beta
                    float d = __fmul_rn(__fsub_rn(y, vm[j]), 0.5f); // (y-v)/2.0
                    vm[j] = __fadd_rn(vm[j], d);                    // v += ...
                    bool sp = (vm[j] >= 1.0f);
                    o[j] = sp ? 1.0f : 0.0f;
                    if (sp) vm[j] = 0.0f;                           // hard reset
                }
                __builtin_nontemporal_store(o,
                    reinterpret_cast<f32x4*>(&out[(size_t)t * BEV + gi]));
            }
        }
        __syncthreads();
    }
}

__global__ void __launch_bounds__(TPB, 2)
k_fused(const float* __restrict__ x, const float* __restrict__ W,
        const float* __restrict__ g, const float* __restrict__ bta,
        float* __restrict__ ws, float* __restrict__ out) {
    __shared__ float sm[NB + 32];    // 1632 floats: covers 350 / 1625 / 1600
    cg::grid_group gr = cg::this_grid();
    float* bs = out;                 // scratch region; phase 5 overwrites all

    phase_bs<0>(x, W, ws, bs, sm);
    __threadfence(); gr.sync(); __threadfence();
    phase_comb<0>(bs, ws, sm);
    __threadfence(); gr.sync(); __threadfence();
    phase_bs<1>(x, W, ws, bs, sm);
    __threadfence(); gr.sync(); __threadfence();
    phase_comb<1>(bs, ws, sm);
    __threadfence(); gr.sync(); __threadfence();
    phase_main(x, W, g, bta, ws, out, sm);
}

extern "C" void kernel_launch(void* const* d_in, const int* in_sizes, int n_in,
                              void* d_out, int out_size, void* d_ws, size_t ws_size,
                              hipStream_t stream) {
    (void)in_sizes; (void)n_in; (void)out_size; (void)ws_size;
    const float* x  = (const float*)d_in[0];
    const float* W  = (const float*)d_in[1];
    const float* g  = (const float*)d_in[2];
    const float* bb = (const float*)d_in[3];
    float* ws  = (float*)d_ws;       // 2 KB: mean[256], rstd[256]
    float* out = (float*)d_out;

    void* args[] = {(void*)&x, (void*)&W, (void*)&g, (void*)&bb,
                    (void*)&ws, (void*)&out};
    hipLaunchCooperativeKernel((void*)k_fused, dim3(GRID), dim3(TPB),
                               args, 0, stream);
}

// Round 4
// 244.335 us; speedup vs baseline: 2.9632x; 2.9632x over previous
//
#include <hip/hip_runtime.h>
#include <math.h>

// Bit-exact np-ref emulation (pinned R14, PASSING since):
//  - einsum: SOP fl(fl(w0x0)+fl(w1x1))  (no FMA)
//  - reduce: numpy BUFFERED reduce: per channel, 25 chunks of 8192; chunk =
//    64 leaves of 128-elem 8-acc blocks, balanced tree; chunks sequential.
//    var two-pass. rstd = fdiv(1,fsqrt(var+eps)). LIF fp32, each op rounded.
// R20 finding: measured dur includes the harness's ~131us output re-poison
//  fill; the 5-kernel pipeline itself is ~128us. Optimization surface is the
//  kernels, not dispatch structure (coop fusion at low occupancy = 2.2x WORSE).
// R21 (this round; per-element values and rounding order IDENTICAL):
//  - k_bs: stage x TRANSPOSED into position-major LDS (sm0[k]=x0, sm1[k]=x1),
//    hot loop reads 4 iters' operands via two aligned ds_read_b128 -> LDS
//    instr 4x fewer (256->64/wave), no v-wrap chain in the hot loop.
//  - k_comb/k_main unchanged from R19 (k_main proven write-floor-bound).
constexpr int T = 16, B = 512, C = 2, V = 25, E = 256;
constexpr int EV  = E * V;           // 6400
constexpr int BEV = B * EV;          // 3,276,800
constexpr int XT  = B * C * V;       // 25600 floats between t-slices of x
constexpr int NB  = 1600;            // 128-element blocks per channel
constexpr int CHUNKS = 25;           // 204800 / 8192
constexpr int BPC = 64;              // 128-blocks per chunk
constexpr float NF = 204800.0f;

typedef float f32x4 __attribute__((ext_vector_type(4)));

#define WS_M32(ws) ((float*)(ws))
#define WS_R32(ws) ((float*)(ws) + E)

// ---- stage 1: per-(p,e) 128-element block-sum; bs layout [p][e] ----
// Position-major staged: sm0[k] = x[row(q)*50 + v(q)], sm1[k] = x[...+25],
// q = p*128+k. Same values the old row-major sm[off]/sm[off+25] delivered.
template<int PASS>
__global__ void __launch_bounds__(256) k_bs(const float* __restrict__ x,
                                            const float* __restrict__ W,
                                            const float* __restrict__ ws,
                                            float* __restrict__ bs) {
    __shared__ __align__(16) float sm0[128];
    __shared__ __align__(16) float sm1[128];
    int p  = blockIdx.x;             // q-block [p*128, p*128+128)
    int q0 = p * 128;
    {
        int i = threadIdx.x;         // 0..255; waves 0-1 -> x0, waves 2-3 -> x1
        int k = i & 127;
        int q = q0 + k;
        int row = q / 25;            // magic-mul div
        // x[row*50 + (q - row*25)] == x[25*row + q]; +25 for the c=1 half
        float val = x[25 * row + q + ((i < 128) ? 0 : 25)];
        if (i < 128) sm0[k] = val; else sm1[k] = val;
    }
    __syncthreads();

    int e = threadIdx.x;             // one thread per channel
    float w0 = W[e * 2 + 0];
    float w1 = W[e * 2 + 1];
    float mn = (PASS == 1) ? WS_M32(ws)[e] : 0.0f;

    float r[8];
    #pragma unroll
    for (int m = 0; m < 32; m++) {   // 2x ds_read_b128 per 4 iterations
        f32x4 a4 = *reinterpret_cast<const f32x4*>(&sm0[4 * m]);
        f32x4 b4 = *reinterpret_cast<const f32x4*>(&sm1[4 * m]);
        #pragma unroll
        for (int j2 = 0; j2 < 4; j2++) {
            int k = 4 * m + j2;      // ascending k: identical order to before
            float y = __fadd_rn(__fmul_rn(w0, a4[j2]), __fmul_rn(w1, b4[j2]));
            if (PASS == 1) {
                float d = __fsub_rn(y, mn);
                y = __fmul_rn(d, d);
            }
            int j = k & 7;
            r[j] = (k < 8) ? y : __fadd_rn(r[j], y);   // numpy 8-acc pattern
        }
    }
    bs[p * 256 + e] =
        __fadd_rn(__fadd_rn(__fadd_rn(r[0], r[1]), __fadd_rn(r[2], r[3])),
                  __fadd_rn(__fadd_rn(r[4], r[5]), __fadd_rn(r[6], r[7])));
}

// ---- stage 2: per-channel combine; register tree (no scratch) ----
template<int WHICH>
__global__ void __launch_bounds__(256) k_comb(const float* __restrict__ bs,
                                              float* __restrict__ ws) {
    __shared__ float cb[NB];
    __shared__ float csum[CHUNKS];
    int e = blockIdx.x;
    for (int i = threadIdx.x; i < NB; i += 256) cb[i] = bs[i * 256 + e];
    __syncthreads();
    if (threadIdx.x < CHUNKS) {
        int c = threadIdx.x;
        float t[BPC];                       // fully-unrolled -> VGPRs
        #pragma unroll
        for (int i = 0; i < BPC; i++) t[i] = cb[c * BPC + i];
        #pragma unroll
        for (int m = BPC / 2; m >= 1; m >>= 1) {    // balanced tree == numpy
            #pragma unroll
            for (int i = 0; i < m; i++)
                t[i] = __fadd_rn(t[2 * i], t[2 * i + 1]);
        }
        csum[c] = t[0];
    }
    __syncthreads();
    if (threadIdx.x == 0) {
        float acc = 0.0f;                   // identity init
        #pragma unroll
        for (int c = 0; c < CHUNKS; c++) acc = __fadd_rn(acc, csum[c]);
        if (WHICH == 0) {
            WS_M32(ws)[e] = __fdiv_rn(acc, NF);
        } else {
            float var = __fdiv_rn(acc, NF);
            WS_R32(ws)[e] = __fdiv_rn(1.0f, __fsqrt_rn(__fadd_rn(var, 1e-5f)));
        }
    }
}

// ---- stage 3: LIF + BN apply; 4 elems/thread, vec4 nontemporal stores ----
__global__ void __launch_bounds__(256) k_main(const float* __restrict__ x,
                                              const float* __restrict__ W,
                                              const float* __restrict__ g,
                                              const float* __restrict__ bta,
                                              const float* __restrict__ ws,
                                              float* __restrict__ out) {
    __shared__ float sx[2 * T * 50];  // up to two b's of x[b,t,c,v], 6.4 KB
    int blk = blockIdx.x;             // 3200 blocks; 1024 idx per block
    int gi0 = blk * 1024;
    int b0  = gi0 / EV;
    int nb  = ((gi0 + 1023) / EV == b0) ? 1 : 2;   // blocks straddle <=2 b's
    for (int i = threadIdx.x; i < nb * 800; i += 256) {
        int bi  = i / 800;
        int r   = i - bi * 800;
        int tt  = r / 50;
        sx[i] = x[(b0 + bi) * 50 + tt * XT + (r - tt * 50)];
    }
    __syncthreads();

    int gi  = gi0 + threadIdx.x * 4;  // 4 consecutive global (b,e,v) indices
    int b   = gi / EV;
    int rem = gi - b * EV;
    int e0  = rem / V;
    int v0  = rem - e0 * V;
    int sb  = (b - b0) * 800;
    int e1  = (e0 < E - 1) ? e0 + 1 : e0;   // channel after a v-wrap
    float w00 = W[e0 * 2], w01 = W[e0 * 2 + 1];
    float w10 = W[e1 * 2], w11 = W[e1 * 2 + 1];
    float mn0 = WS_M32(ws)[e0], mn1 = WS_M32(ws)[e1];
    float rs0 = WS_R32(ws)[e0], rs1 = WS_R32(ws)[e1];
    float ga0 = g[e0],  ga1 = g[e1];        // == 1.0f: exact no-op
    float be0 = bta[e0], be1 = bta[e1];     // == 0.0f: exact no-op

    float wA[4], wB[4], mn[4], rs[4], ga[4], be[4];
    int   vv[4];
    #pragma unroll
    for (int j = 0; j < 4; j++) {           // static indices -> registers
        int  vj = v0 + j;
        bool cr = (vj >= V);                // crossed into channel e0+1
        vv[j] = cr ? vj - V : vj;
        wA[j] = cr ? w10 : w00;  wB[j] = cr ? w11 : w01;
        mn[j] = cr ? mn1 : mn0;  rs[j] = cr ? rs1 : rs0;
        ga[j] = cr ? ga1 : ga0;  be[j] = cr ? be1 : be0;
    }

    float vm[4] = {0.0f, 0.0f, 0.0f, 0.0f};
    #pragma unroll
    for (int t = 0; t < T; t++) {
        f32x4 o;
        #pragma unroll
        for (int j = 0; j < 4; j++) {
            float x0 = sx[sb + t * 50 + vv[j]];
            float x1 = sx[sb + t * 50 + 25 + vv[j]];
            float y = __fadd_rn(__fmul_rn(wA[j], x0), __fmul_rn(wB[j], x1));
            y = __fmul_rn(__fsub_rn(y, mn[j]), rs[j]);      // (y-mean)*rstd
            y = __fadd_rn(__fmul_rn(y, ga[j]), be[j]);      // *gamma+beta
            float d = __fmul_rn(__fsub_rn(y, vm[j]), 0.5f); // (y-v)/2.0
            vm[j] = __fadd_rn(vm[j], d);                    // v += ...
            bool sp = (vm[j] >= 1.0f);
            o[j] = sp ? 1.0f : 0.0f;
            if (sp) vm[j] = 0.0f;                           // hard reset
        }
        __builtin_nontemporal_store(o,
            reinterpret_cast<f32x4*>(&out[(size_t)t * BEV + gi]));
    }
}

extern "C" void kernel_launch(void* const* d_in, const int* in_sizes, int n_in,
                              void* d_out, int out_size, void* d_ws, size_t ws_size,
                              hipStream_t stream) {
    (void)in_sizes; (void)n_in; (void)out_size; (void)ws_size;
    const float* x  = (const float*)d_in[0];
    const float* W  = (const float*)d_in[1];
    const float* g  = (const float*)d_in[2];
    const float* bb = (const float*)d_in[3];
    float* ws = (float*)d_ws;        // 2 KB: mean[256], rstd[256]
    float* bs = (float*)d_out;       // scratch 1.6 MB; k_main overwrites all

    k_bs<0><<<NB, 256, 0, stream>>>(x, W, ws, bs);
    k_comb<0><<<E, 256, 0, stream>>>(bs, ws);
    k_bs<1><<<NB, 256, 0, stream>>>(x, W, ws, bs);
    k_comb<1><<<E, 256, 0, stream>>>(bs, ws);
    k_main<<<BEV / 1024, 256, 0, stream>>>(x, W, g, bb, ws, (float*)d_out);
}

// Round 5
// 243.370 us; speedup vs baseline: 2.9750x; 1.0040x over previous
//
#include <hip/hip_runtime.h>
#include <math.h>

// Bit-exact np-ref emulation (pinned R14, PASSING since):
//  - einsum: SOP fl(fl(w0x0)+fl(w1x1))  (no FMA)
//  - reduce: numpy BUFFERED reduce: per channel, 25 chunks of 8192; chunk =
//    64 leaves of 128-elem 8-acc blocks, balanced tree; chunks sequential.
//    var two-pass. rstd = fdiv(1,fsqrt(var+eps)). LIF fp32, each op rounded.
// R20 finding: measured dur includes the harness's ~131us output re-poison
//  fill; the 5-kernel pipeline itself is ~113us. Optimize kernels, not launch
//  structure (coop fusion at low occupancy = 2.2x WORSE).
// R21 (+15us): k_bs position-major LDS, ds_read_b128 broadcast delivery.
// R22 (this round; per-element values and rounding order IDENTICAL):
//  - k_bs: 64-thread blocks, 4 channels/thread (e = tid + 64u). Each wave
//    issues the 64 uniform-broadcast b128 reads ONCE (was 4x redundant
//    across 4 waves) and reuses each read for 4 channels of VALU.
//    LDS-pipe load per block: 256 -> 64 b128 instrs.
constexpr int T = 16, B = 512, C = 2, V = 25, E = 256;
constexpr int EV  = E * V;           // 6400
constexpr int BEV = B * EV;          // 3,276,800
constexpr int XT  = B * C * V;       // 25600 floats between t-slices of x
constexpr int NB  = 1600;            // 128-element blocks per channel
constexpr int CHUNKS = 25;           // 204800 / 8192
constexpr int BPC = 64;              // 128-blocks per chunk
constexpr float NF = 204800.0f;

typedef float f32x4 __attribute__((ext_vector_type(4)));

#define WS_M32(ws) ((float*)(ws))
#define WS_R32(ws) ((float*)(ws) + E)

// ---- stage 1: per-(p,e) 128-element block-sum; bs layout [p][e] ----
// Position-major staged: sm0[k] = x[row(q)*50 + v(q)], sm1[k] = x[...+25],
// q = p*128+k. One 64-thread wave; 4 channels per thread.
template<int PASS>
__global__ void __launch_bounds__(64) k_bs(const float* __restrict__ x,
                                           const float* __restrict__ W,
                                           const float* __restrict__ ws,
                                           float* __restrict__ bs) {
    __shared__ __align__(16) float sm0[128];
    __shared__ __align__(16) float sm1[128];
    int p  = blockIdx.x;             // q-block [p*128, p*128+128)
    int q0 = p * 128;
    {
        int tid = threadIdx.x;       // 0..63
        // x[row*50 + (q - row*25)] == x[25*row + q]; +25 for the c=1 half
        int qA = q0 + tid;           int rA = qA / 25;
        int qB = q0 + tid + 64;      int rB = qB / 25;
        sm0[tid]      = x[25 * rA + qA];
        sm0[tid + 64] = x[25 * rB + qB];
        sm1[tid]      = x[25 * rA + qA + 25];
        sm1[tid + 64] = x[25 * rB + qB + 25];
    }
    __syncthreads();

    float w0[4], w1[4], mn[4];
    #pragma unroll
    for (int u = 0; u < 4; u++) {    // channels e = tid + 64u
        int e = threadIdx.x + 64 * u;
        w0[u] = W[e * 2 + 0];
        w1[u] = W[e * 2 + 1];
        mn[u] = (PASS == 1) ? WS_M32(ws)[e] : 0.0f;
    }

    float r[4][8];                   // all indices compile-time -> VGPRs
    #pragma unroll
    for (int m = 0; m < 32; m++) {   // 2x broadcast ds_read_b128 per 4 iters
        f32x4 a4 = *reinterpret_cast<const f32x4*>(&sm0[4 * m]);
        f32x4 b4 = *reinterpret_cast<const f32x4*>(&sm1[4 * m]);
        #pragma unroll
        for (int j2 = 0; j2 < 4; j2++) {
            int k = 4 * m + j2;      // ascending k: identical order per channel
            int j = k & 7;
            #pragma unroll
            for (int u = 0; u < 4; u++) {
                float y = __fadd_rn(__fmul_rn(w0[u], a4[j2]),
                                    __fmul_rn(w1[u], b4[j2]));
                if (PASS == 1) {
                    float d = __fsub_rn(y, mn[u]);
                    y = __fmul_rn(d, d);
                }
                r[u][j] = (k < 8) ? y : __fadd_rn(r[u][j], y); // numpy 8-acc
            }
        }
    }
    #pragma unroll
    for (int u = 0; u < 4; u++) {
        bs[p * 256 + threadIdx.x + 64 * u] =
            __fadd_rn(__fadd_rn(__fadd_rn(r[u][0], r[u][1]),
                                __fadd_rn(r[u][2], r[u][3])),
                      __fadd_rn(__fadd_rn(r[u][4], r[u][5]),
                                __fadd_rn(r[u][6], r[u][7])));
    }
}

// ---- stage 2: per-channel combine; register tree (no scratch) ----
template<int WHICH>
__global__ void __launch_bounds__(256) k_comb(const float* __restrict__ bs,
                                              float* __restrict__ ws) {
    __shared__ float cb[NB];
    __shared__ float csum[CHUNKS];
    int e = blockIdx.x;
    for (int i = threadIdx.x; i < NB; i += 256) cb[i] = bs[i * 256 + e];
    __syncthreads();
    if (threadIdx.x < CHUNKS) {
        int c = threadIdx.x;
        float t[BPC];                       // fully-unrolled -> VGPRs
        #pragma unroll
        for (int i = 0; i < BPC; i++) t[i] = cb[c * BPC + i];
        #pragma unroll
        for (int m = BPC / 2; m >= 1; m >>= 1) {    // balanced tree == numpy
            #pragma unroll
            for (int i = 0; i < m; i++)
                t[i] = __fadd_rn(t[2 * i], t[2 * i + 1]);
        }
        csum[c] = t[0];
    }
    __syncthreads();
    if (threadIdx.x == 0) {
        float acc = 0.0f;                   // identity init
        #pragma unroll
        for (int c = 0; c < CHUNKS; c++) acc = __fadd_rn(acc, csum[c]);
        if (WHICH == 0) {
            WS_M32(ws)[e] = __fdiv_rn(acc, NF);
        } else {
            float var = __fdiv_rn(acc, NF);
            WS_R32(ws)[e] = __fdiv_rn(1.0f, __fsqrt_rn(__fadd_rn(var, 1e-5f)));
        }
    }
}

// ---- stage 3: LIF + BN apply; 4 elems/thread, vec4 nontemporal stores ----
__global__ void __launch_bounds__(256) k_main(const float* __restrict__ x,
                                              const float* __restrict__ W,
                                              const float* __restrict__ g,
                                              const float* __restrict__ bta,
                                              const float* __restrict__ ws,
                                              float* __restrict__ out) {
    __shared__ float sx[2 * T * 50];  // up to two b's of x[b,t,c,v], 6.4 KB
    int blk = blockIdx.x;             // 3200 blocks; 1024 idx per block
    int gi0 = blk * 1024;
    int b0  = gi0 / EV;
    int nb  = ((gi0 + 1023) / EV == b0) ? 1 : 2;   // blocks straddle <=2 b's
    for (int i = threadIdx.x; i < nb * 800; i += 256) {
        int bi  = i / 800;
        int r   = i - bi * 800;
        int tt  = r / 50;
        sx[i] = x[(b0 + bi) * 50 + tt * XT + (r - tt * 50)];
    }
    __syncthreads();

    int gi  = gi0 + threadIdx.x * 4;  // 4 consecutive global (b,e,v) indices
    int b   = gi / EV;
    int rem = gi - b * EV;
    int e0  = rem / V;
    int v0  = rem - e0 * V;
    int sb  = (b - b0) * 800;
    int e1  = (e0 < E - 1) ? e0 + 1 : e0;   // channel after a v-wrap
    float w00 = W[e0 * 2], w01 = W[e0 * 2 + 1];
    float w10 = W[e1 * 2], w11 = W[e1 * 2 + 1];
    float mn0 = WS_M32(ws)[e0], mn1 = WS_M32(ws)[e1];
    float rs0 = WS_R32(ws)[e0], rs1 = WS_R32(ws)[e1];
    float ga0 = g[e0],  ga1 = g[e1];        // == 1.0f: exact no-op
    float be0 = bta[e0], be1 = bta[e1];     // == 0.0f: exact no-op

    float wA[4], wB[4], mn[4], rs[4], ga[4], be[4];
    int   vv[4];
    #pragma unroll
    for (int j = 0; j < 4; j++) {           // static indices -> registers
        int  vj = v0 + j;
        bool cr = (vj >= V);                // crossed into channel e0+1
        vv[j] = cr ? vj - V : vj;
        wA[j] = cr ? w10 : w00;  wB[j] = cr ? w11 : w01;
        mn[j] = cr ? mn1 : mn0;  rs[j] = cr ? rs1 : rs0;
        ga[j] = cr ? ga1 : ga0;  be[j] = cr ? be1 : be0;
    }

    float vm[4] = {0.0f, 0.0f, 0.0f, 0.0f};
    #pragma unroll
    for (int t = 0; t < T; t++) {
        f32x4 o;
        #pragma unroll
        for (int j = 0; j < 4; j++) {
            float x0 = sx[sb + t * 50 + vv[j]];
            float x1 = sx[sb + t * 50 + 25 + vv[j]];
            float y = __fadd_rn(__fmul_rn(wA[j], x0), __fmul_rn(wB[j], x1));
            y = __fmul_rn(__fsub_rn(y, mn[j]), rs[j]);      // (y-mean)*rstd
            y = __fadd_rn(__fmul_rn(y, ga[j]), be[j]);      // *gamma+beta
            float d = __fmul_rn(__fsub_rn(y, vm[j]), 0.5f); // (y-v)/2.0
            vm[j] = __fadd_rn(vm[j], d);                    // v += ...
            bool sp = (vm[j] >= 1.0f);
            o[j] = sp ? 1.0f : 0.0f;
            if (sp) vm[j] = 0.0f;                           // hard reset
        }
        __builtin_nontemporal_store(o,
            reinterpret_cast<f32x4*>(&out[(size_t)t * BEV + gi]));
    }
}

extern "C" void kernel_launch(void* const* d_in, const int* in_sizes, int n_in,
                              void* d_out, int out_size, void* d_ws, size_t ws_size,
                              hipStream_t stream) {
    (void)in_sizes; (void)n_in; (void)out_size; (void)ws_size;
    const float* x  = (const float*)d_in[0];
    const float* W  = (const float*)d_in[1];
    const float* g  = (const float*)d_in[2];
    const float* bb = (const float*)d_in[3];
    float* ws = (float*)d_ws;        // 2 KB: mean[256], rstd[256]
    float* bs = (float*)d_out;       // scratch 1.6 MB; k_main overwrites all

    k_bs<0><<<NB, 64, 0, stream>>>(x, W, ws, bs);
    k_comb<0><<<E, 256, 0, stream>>>(bs, ws);
    k_bs<1><<<NB, 64, 0, stream>>>(x, W, ws, bs);
    k_comb<1><<<E, 256, 0, stream>>>(bs, ws);
    k_main<<<BEV / 1024, 256, 0, stream>>>(x, W, g, bb, ws, (float*)d_out);
}

// Round 6
// 233.479 us; speedup vs baseline: 3.1010x; 1.0424x over previous
//
#include <hip/hip_runtime.h>
#include <math.h>

// Bit-exact np-ref emulation (pinned R14, PASSING since):
//  - einsum: SOP fl(fl(w0x0)+fl(w1x1))  (no FMA)
//  - reduce: numpy BUFFERED reduce: per channel, 25 chunks of 8192; chunk =
//    64 leaves of 128-elem 8-acc blocks, balanced tree; chunks sequential.
//    var two-pass. rstd = fdiv(1,fsqrt(var+eps)). LIF fp32, each op rounded.
// R20 finding: measured dur includes the harness's ~131us output re-poison
//  fill; the 5-kernel pipeline itself is ~112us. Single-launch residual was
//  only ~23us -> launch gaps are small; suspicion on k_main > write floor.
// R21 (+15us): k_bs position-major LDS, ds_read_b128 broadcast delivery.
// R22 (+1us): k_bs 4 channels/thread — k_bs now at its floor; stop there.
// R23 (this round): k_main stores CACHED instead of nontemporal. Output is
//  209.7 MB and FITS the 256 MB L3; nt forced every byte through the
//  <=6.3 TB/s HBM path. Values stored are identical -> absmax 0.0.
constexpr int T = 16, B = 512, C = 2, V = 25, E = 256;
constexpr int EV  = E * V;           // 6400
constexpr int BEV = B * EV;          // 3,276,800
constexpr int XT  = B * C * V;       // 25600 floats between t-slices of x
constexpr int NB  = 1600;            // 128-element blocks per channel
constexpr int CHUNKS = 25;           // 204800 / 8192
constexpr int BPC = 64;              // 128-blocks per chunk
constexpr float NF = 204800.0f;

typedef float f32x4 __attribute__((ext_vector_type(4)));

#define WS_M32(ws) ((float*)(ws))
#define WS_R32(ws) ((float*)(ws) + E)

// ---- stage 1: per-(p,e) 128-element block-sum; bs layout [p][e] ----
// Position-major staged: sm0[k] = x[row(q)*50 + v(q)], sm1[k] = x[...+25],
// q = p*128+k. One 64-thread wave; 4 channels per thread.
template<int PASS>
__global__ void __launch_bounds__(64) k_bs(const float* __restrict__ x,
                                           const float* __restrict__ W,
                                           const float* __restrict__ ws,
                                           float* __restrict__ bs) {
    __shared__ __align__(16) float sm0[128];
    __shared__ __align__(16) float sm1[128];
    int p  = blockIdx.x;             // q-block [p*128, p*128+128)
    int q0 = p * 128;
    {
        int tid = threadIdx.x;       // 0..63
        // x[row*50 + (q - row*25)] == x[25*row + q]; +25 for the c=1 half
        int qA = q0 + tid;           int rA = qA / 25;
        int qB = q0 + tid + 64;      int rB = qB / 25;
        sm0[tid]      = x[25 * rA + qA];
        sm0[tid + 64] = x[25 * rB + qB];
        sm1[tid]      = x[25 * rA + qA + 25];
        sm1[tid + 64] = x[25 * rB + qB + 25];
    }
    __syncthreads();

    float w0[4], w1[4], mn[4];
    #pragma unroll
    for (int u = 0; u < 4; u++) {    // channels e = tid + 64u
        int e = threadIdx.x + 64 * u;
        w0[u] = W[e * 2 + 0];
        w1[u] = W[e * 2 + 1];
        mn[u] = (PASS == 1) ? WS_M32(ws)[e] : 0.0f;
    }

    float r[4][8];                   // all indices compile-time -> VGPRs
    #pragma unroll
    for (int m = 0; m < 32; m++) {   // 2x broadcast ds_read_b128 per 4 iters
        f32x4 a4 = *reinterpret_cast<const f32x4*>(&sm0[4 * m]);
        f32x4 b4 = *reinterpret_cast<const f32x4*>(&sm1[4 * m]);
        #pragma unroll
        for (int j2 = 0; j2 < 4; j2++) {
            int k = 4 * m + j2;      // ascending k: identical order per channel
            int j = k & 7;
            #pragma unroll
            for (int u = 0; u < 4; u++) {
                float y = __fadd_rn(__fmul_rn(w0[u], a4[j2]),
                                    __fmul_rn(w1[u], b4[j2]));
                if (PASS == 1) {
                    float d = __fsub_rn(y, mn[u]);
                    y = __fmul_rn(d, d);
                }
                r[u][j] = (k < 8) ? y : __fadd_rn(r[u][j], y); // numpy 8-acc
            }
        }
    }
    #pragma unroll
    for (int u = 0; u < 4; u++) {
        bs[p * 256 + threadIdx.x + 64 * u] =
            __fadd_rn(__fadd_rn(__fadd_rn(r[u][0], r[u][1]),
                                __fadd_rn(r[u][2], r[u][3])),
                      __fadd_rn(__fadd_rn(r[u][4], r[u][5]),
                                __fadd_rn(r[u][6], r[u][7])));
    }
}

// ---- stage 2: per-channel combine; register tree (no scratch) ----
template<int WHICH>
__global__ void __launch_bounds__(256) k_comb(const float* __restrict__ bs,
                                              float* __restrict__ ws) {
    __shared__ float cb[NB];
    __shared__ float csum[CHUNKS];
    int e = blockIdx.x;
    for (int i = threadIdx.x; i < NB; i += 256) cb[i] = bs[i * 256 + e];
    __syncthreads();
    if (threadIdx.x < CHUNKS) {
        int c = threadIdx.x;
        float t[BPC];                       // fully-unrolled -> VGPRs
        #pragma unroll
        for (int i = 0; i < BPC; i++) t[i] = cb[c * BPC + i];
        #pragma unroll
        for (int m = BPC / 2; m >= 1; m >>= 1) {    // balanced tree == numpy
            #pragma unroll
            for (int i = 0; i < m; i++)
                t[i] = __fadd_rn(t[2 * i], t[2 * i + 1]);
        }
        csum[c] = t[0];
    }
    __syncthreads();
    if (threadIdx.x == 0) {
        float acc = 0.0f;                   // identity init
        #pragma unroll
        for (int c = 0; c < CHUNKS; c++) acc = __fadd_rn(acc, csum[c]);
        if (WHICH == 0) {
            WS_M32(ws)[e] = __fdiv_rn(acc, NF);
        } else {
            float var = __fdiv_rn(acc, NF);
            WS_R32(ws)[e] = __fdiv_rn(1.0f, __fsqrt_rn(__fadd_rn(var, 1e-5f)));
        }
    }
}

// ---- stage 3: LIF + BN apply; 4 elems/thread, CACHED vec4 stores ----
__global__ void __launch_bounds__(256) k_main(const float* __restrict__ x,
                                              const float* __restrict__ W,
                                              const float* __restrict__ g,
                                              const float* __restrict__ bta,
                                              const float* __restrict__ ws,
                                              float* __restrict__ out) {
    __shared__ float sx[2 * T * 50];  // up to two b's of x[b,t,c,v], 6.4 KB
    int blk = blockIdx.x;             // 3200 blocks; 1024 idx per block
    int gi0 = blk * 1024;
    int b0  = gi0 / EV;
    int nb  = ((gi0 + 1023) / EV == b0) ? 1 : 2;   // blocks straddle <=2 b's
    for (int i = threadIdx.x; i < nb * 800; i += 256) {
        int bi  = i / 800;
        int r   = i - bi * 800;
        int tt  = r / 50;
        sx[i] = x[(b0 + bi) * 50 + tt * XT + (r - tt * 50)];
    }
    __syncthreads();

    int gi  = gi0 + threadIdx.x * 4;  // 4 consecutive global (b,e,v) indices
    int b   = gi / EV;
    int rem = gi - b * EV;
    int e0  = rem / V;
    int v0  = rem - e0 * V;
    int sb  = (b - b0) * 800;
    int e1  = (e0 < E - 1) ? e0 + 1 : e0;   // channel after a v-wrap
    float w00 = W[e0 * 2], w01 = W[e0 * 2 + 1];
    float w10 = W[e1 * 2], w11 = W[e1 * 2 + 1];
    float mn0 = WS_M32(ws)[e0], mn1 = WS_M32(ws)[e1];
    float rs0 = WS_R32(ws)[e0], rs1 = WS_R32(ws)[e1];
    float ga0 = g[e0],  ga1 = g[e1];        // == 1.0f: exact no-op
    float be0 = bta[e0], be1 = bta[e1];     // == 0.0f: exact no-op

    float wA[4], wB[4], mn[4], rs[4], ga[4], be[4];
    int   vv[4];
    #pragma unroll
    for (int j = 0; j < 4; j++) {           // static indices -> registers
        int  vj = v0 + j;
        bool cr = (vj >= V);                // crossed into channel e0+1
        vv[j] = cr ? vj - V : vj;
        wA[j] = cr ? w10 : w00;  wB[j] = cr ? w11 : w01;
        mn[j] = cr ? mn1 : mn0;  rs[j] = cr ? rs1 : rs0;
        ga[j] = cr ? ga1 : ga0;  be[j] = cr ? be1 : be0;
    }

    float vm[4] = {0.0f, 0.0f, 0.0f, 0.0f};
    #pragma unroll
    for (int t = 0; t < T; t++) {
        f32x4 o;
        #pragma unroll
        for (int j = 0; j < 4; j++) {
            float x0 = sx[sb + t * 50 + vv[j]];
            float x1 = sx[sb + t * 50 + 25 + vv[j]];
            float y = __fadd_rn(__fmul_rn(wA[j], x0), __fmul_rn(wB[j], x1));
            y = __fmul_rn(__fsub_rn(y, mn[j]), rs[j]);      // (y-mean)*rstd
            y = __fadd_rn(__fmul_rn(y, ga[j]), be[j]);      // *gamma+beta
            float d = __fmul_rn(__fsub_rn(y, vm[j]), 0.5f); // (y-v)/2.0
            vm[j] = __fadd_rn(vm[j], d);                    // v += ...
            bool sp = (vm[j] >= 1.0f);
            o[j] = sp ? 1.0f : 0.0f;
            if (sp) vm[j] = 0.0f;                           // hard reset
        }
        // CACHED store (R23): output (210 MB) fits the 256 MB L3; the old
        // nontemporal hint forced the slow HBM path for every byte.
        *reinterpret_cast<f32x4*>(&out[(size_t)t * BEV + gi]) = o;
    }
}

extern "C" void kernel_launch(void* const* d_in, const int* in_sizes, int n_in,
                              void* d_out, int out_size, void* d_ws, size_t ws_size,
                              hipStream_t stream) {
    (void)in_sizes; (void)n_in; (void)out_size; (void)ws_size;
    const float* x  = (const float*)d_in[0];
    const float* W  = (const float*)d_in[1];
    const float* g  = (const float*)d_in[2];
    const float* bb = (const float*)d_in[3];
    float* ws = (float*)d_ws;        // 2 KB: mean[256], rstd[256]
    float* bs = (float*)d_out;       // scratch 1.6 MB; k_main overwrites all

    k_bs<0><<<NB, 64, 0, stream>>>(x, W, ws, bs);
    k_comb<0><<<E, 256, 0, stream>>>(bs, ws);
    k_bs<1><<<NB, 64, 0, stream>>>(x, W, ws, bs);
    k_comb<1><<<E, 256, 0, stream>>>(bs, ws);
    k_main<<<BEV / 1024, 256, 0, stream>>>(x, W, g, bb, ws, (float*)d_out);
}